// Round 6
// baseline (449.470 us; speedup 1.0000x reference)
//
#include <hip/hip_runtime.h>
#include <math.h>

// L = 2*pi * log2(e): exp(-2pi r^2) == exp2(-L r^2)
#define LCONST 9.064720283654388f

// dom binned into 5x5x5 cells (size 2.0) over [0,10)^3; C1/C binned by (x,y)
// COLUMN only (25 columns). A cell's scan = <=9 CONTIGUOUS column runs; the
// missing z-filter is free because out-of-cutoff pairs underflow exp2 to 0.
// Cutoff r=2: dropped terms ~1.2e-11 vs theta ~0.36 -> below f32 ulp: exact.
#define NC 5
#define NCELL 125
#define NCOL 25
#define DOMCAP 192   // dom/cell: mean 131, sigma 11.4 -> +5.3 sigma (r2-r5 passed)
#define COLCAP 96    // C1 pts/(b,col): mean 41, sigma 6.4 -> +8.6 sigma; mult of 8
#define NB 16
#define GRID1 132              // 132*256 = 33792 = exactly all points to bin
#define MAIN_BLOCKS 4500
#define NTASK (MAIN_BLOCKS * 4)  // 18000 = 16 b x 125 cell x 3 chunk x 3 x-slab
#define DUMMYW -1.0e30f        // pad point w: arg=-1e30 -> exp2=0 exactly, no NaN

// cnts word layout
#define W_CNTD 0      // 125
#define W_CNTC1 125   // 16*25 = 400
#define W_CNTC 525    // 25
#define W_PROD 550    // 16 floats
#define W_DONE 566    // ticket
#define W_BAR1 567    // spin barrier (post-binning)
#define W_BAR2 568    // spin barrier (post-padding)
#define W_TOTAL 569

__device__ __forceinline__ float fexp2(float x) {
#if defined(__has_builtin)
#if __has_builtin(__builtin_amdgcn_exp2f)
    return __builtin_amdgcn_exp2f(x);
#else
    return exp2f(x);
#endif
#else
    return exp2f(x);
#endif
}

__device__ __forceinline__ int clamp5(float v) {
    int c = (int)(v * 0.5f);
    return c < 0 ? 0 : (c > NC - 1 ? NC - 1 : c);
}

// Full exponent arg = -L||d-q||^2 <= 0 stays in ONE exp2 argument (factoring
// exp2(d.w) out overflows: inf*0=NaN -- round-1 bug).
#define PAIR_ARG(d, q) fmaf((d).x, (q).x, fmaf((d).y, (q).y, fmaf((d).z, (q).z, (d).w + (q).w)))

// Scan one x-slab (<=3 y-columns) of a padded column array. Counts are padded
// to a multiple of 8 with DUMMYW points, so the loop is remainder-free and the
// 8 loads per body are independent -> 8 in flight per wave (round-5 counters
// showed 183 cyc/iter = one L2 latency with only 2 in flight; round-0's
// unroll-8 fixed-trip loop ran at 26 cyc/iter).
__device__ __forceinline__ float scan_slab(float4 d, int x2, int cy,
                                           const float4* __restrict__ cols,
                                           const int* __restrict__ cnt) {
    float a0 = 0.f, a1 = 0.f, a2 = 0.f, a3 = 0.f;
    int ylo = cy > 0 ? cy - 1 : 0;
    int yhi = cy < NC - 1 ? cy + 1 : NC - 1;
    #pragma unroll 1
    for (int y2 = ylo; y2 <= yhi; ++y2) {
        int col = x2 * NC + y2;
        int n8 = __builtin_amdgcn_readfirstlane((min(cnt[col], COLCAP) + 7) & ~7);
        const float4* __restrict__ p = cols + col * COLCAP;
        #pragma unroll 1
        for (int i = 0; i < n8; i += 8) {
            float4 q0 = p[i], q1 = p[i + 1], q2 = p[i + 2], q3 = p[i + 3];
            float4 q4 = p[i + 4], q5 = p[i + 5], q6 = p[i + 6], q7 = p[i + 7];
            a0 += fexp2(PAIR_ARG(d, q0)); a1 += fexp2(PAIR_ARG(d, q1));
            a2 += fexp2(PAIR_ARG(d, q2)); a3 += fexp2(PAIR_ARG(d, q3));
            a0 += fexp2(PAIR_ARG(d, q4)); a1 += fexp2(PAIR_ARG(d, q5));
            a2 += fexp2(PAIR_ARG(d, q6)); a3 += fexp2(PAIR_ARG(d, q7));
        }
    }
    return (a0 + a1) + (a2 + a3);
}

// Phases: bin -> barrier1 -> pad columns to x8 with dummies -> barrier2 ->
// TC = theta_C per dom slot (padded unroll-8 scan, 375 wave-tasks on 528
// waves). Spin barrier: 132 blocks trivially co-resident (round-5 proven).
__global__ void __launch_bounds__(256) k_bin(const float* __restrict__ C1,
                                             const float* __restrict__ C,
                                             const float* __restrict__ dom,
                                             float4* __restrict__ PDbin,
                                             float4* __restrict__ C1col,
                                             float4* __restrict__ Ccol,
                                             float* __restrict__ TC,
                                             int* __restrict__ cnts) {
    int* cntD  = cnts + W_CNTD;
    int* cntC1 = cnts + W_CNTC1;
    int* cntC  = cnts + W_CNTC;
    unsigned* bar1 = (unsigned*)(cnts + W_BAR1);
    unsigned* bar2 = (unsigned*)(cnts + W_BAR2);
    int t = blockIdx.x * 256 + threadIdx.x;   // 0..33791 exactly

    // ---- bin (slot order nondeterministic; sums order-free) ----
    if (t < 16384) {
        float x = dom[3 * t], y = dom[3 * t + 1], z = dom[3 * t + 2];
        int cell = (clamp5(x) * NC + clamp5(y)) * NC + clamp5(z);
        int s = atomicAdd(cntD + cell, 1);
        if (s < DOMCAP)   // clamp: overflowed bins can't OOB
            PDbin[cell * DOMCAP + s] =
                make_float4(2.0f * LCONST * x, 2.0f * LCONST * y, 2.0f * LCONST * z,
                            -LCONST * (x * x + y * y + z * z));
    } else if (t < 32768) {
        int j = t - 16384;
        float x = C1[3 * j], y = C1[3 * j + 1], z = C1[3 * j + 2];
        int b = j >> 10;
        int col = clamp5(x) * NC + clamp5(y);
        int s = atomicAdd(cntC1 + b * NCOL + col, 1);
        if (s < COLCAP)
            C1col[(b * NCOL + col) * COLCAP + s] =
                make_float4(x, y, z, -LCONST * (x * x + y * y + z * z));
    } else {
        int j = t - 32768;
        float x = C[3 * j], y = C[3 * j + 1], z = C[3 * j + 2];
        int col = clamp5(x) * NC + clamp5(y);
        int s = atomicAdd(cntC + col, 1);
        if (s < COLCAP)
            Ccol[col * COLCAP + s] =
                make_float4(x, y, z, -LCONST * (x * x + y * y + z * z));
    }

    // ---- barrier 1 ----
    __syncthreads();
    if (threadIdx.x == 0) {
        __threadfence();
        atomicAdd(bar1, 1u);
        while (atomicAdd(bar1, 0u) < (unsigned)GRID1) {}
        __threadfence();
    }
    __syncthreads();

    // ---- pad all 425 column lists up to a multiple of 8 with dummy points ----
    if (t < 400) {
        int cnt = min(cntC1[t], COLCAP), n8 = (cnt + 7) & ~7;
        for (int s = cnt; s < n8; ++s)
            C1col[t * COLCAP + s] = make_float4(0.f, 0.f, 0.f, DUMMYW);
    } else if (t < 425) {
        int i = t - 400;
        int cnt = min(cntC[i], COLCAP), n8 = (cnt + 7) & ~7;
        for (int s = cnt; s < n8; ++s)
            Ccol[i * COLCAP + s] = make_float4(0.f, 0.f, 0.f, DUMMYW);
    }

    // ---- barrier 2 ----
    __syncthreads();
    if (threadIdx.x == 0) {
        __threadfence();
        atomicAdd(bar2, 1u);
        while (atomicAdd(bar2, 0u) < (unsigned)GRID1) {}
        __threadfence();
    }
    __syncthreads();

    // ---- TC: theta_C per dom slot (375 wave-tasks over 528 waves) ----
    int wv = t >> 6, lane = t & 63;
    for (int task = wv; task < NCELL * 3; task += (GRID1 * 256) / 64) {
        int cell = task / 3, chunk = task % 3;
        int len = __builtin_amdgcn_readfirstlane(min(cntD[cell], DOMCAP)) - chunk * 64;
        if (len > 0) {                        // wave-uniform
            int slot = cell * DOMCAP + chunk * 64 + lane;
            float4 d = make_float4(0.f, 0.f, 0.f, 0.f);   // sanitize poison lanes
            if (lane < len) d = PDbin[slot];
            int cx = cell / 25, cy = (cell / 5) % 5;
            int xlo = cx > 0 ? cx - 1 : 0, xhi = cx < NC - 1 ? cx + 1 : NC - 1;
            float acc = 0.f;
            for (int x2 = xlo; x2 <= xhi; ++x2)
                acc += scan_slab(d, x2, cy, Ccol, cntC);
            TC[slot] = acc;                   // finite for all written slots
        }
    }
}

// Wave task = (b, cell, chunk-of-64, x-slab). Legal split: sum_slot theta_b*TC
// is LINEAR in theta_b's per-column contributions, so each slab's partial
// product atomicAdds independently. 18000 wave-tasks fill the chip.
__global__ void __launch_bounds__(256) k_main(const float4* __restrict__ PDbin,
                                              const float4* __restrict__ C1col,
                                              const float* __restrict__ TC,
                                              int* __restrict__ cnts,
                                              float* __restrict__ out) {
    const int* cntD  = cnts + W_CNTD;
    const int* cntC1 = cnts + W_CNTC1;
    float* prod = (float*)(cnts + W_PROD);
    unsigned* done = (unsigned*)(cnts + W_DONE);

    int lane = threadIdx.x & 63;
    int wt = __builtin_amdgcn_readfirstlane(blockIdx.x * 4 + (threadIdx.x >> 6));
    int b = wt / 1125;
    int r = wt - b * 1125;          // cell*9 + chunk*3 + xr
    int cell = r / 9;
    int s9 = r - cell * 9;
    int chunk = s9 / 3;
    int xr = s9 - chunk * 3;
    int cx = cell / 25, cy = (cell / 5) % 5;
    int x2 = cx - 1 + xr;

    int len = __builtin_amdgcn_readfirstlane(min(cntD[cell], DOMCAP)) - chunk * 64;
    if (len > 0 && (unsigned)x2 < (unsigned)NC) {   // wave-uniform
        int slot = cell * DOMCAP + chunk * 64 + lane;
        float4 d = make_float4(0.f, 0.f, 0.f, 0.f);  // sanitize poison lanes
        if (lane < len) d = PDbin[slot];
        float acc = scan_slab(d, x2, cy, C1col + (size_t)b * (NCOL * COLCAP),
                              cntC1 + b * NCOL);
        float v = (lane < len) ? acc * TC[slot] : 0.0f;  // select: NaN-safe
        for (int off = 32; off; off >>= 1) v += __shfl_down(v, off, 64);
        if (lane == 0) atomicAdd(prod + b, v);
    }

    // ticket finalize (round-4/5 proven): every wave arrives; 18000th writes out.
    __threadfence();
    unsigned old = 0;
    if (lane == 0) old = atomicAdd(done, 1u);
    old = __shfl(old, 0, 64);
    if (old == NTASK - 1) {
        __threadfence();
        if (lane < 16) {
            const float scale = 4.76837158203125e-4f;  // A*V/1024
            float p = atomicAdd(prod + lane, 0.0f);    // coherent read
            float dot = fminf(fmaxf(p * scale, 0.0f), 1.0f);
            out[lane] = 1.0f - dot;
        }
    }
}

extern "C" void kernel_launch(void* const* d_in, const int* in_sizes, int n_in,
                              void* d_out, int out_size, void* d_ws, size_t ws_size,
                              hipStream_t stream) {
    const float* C1  = (const float*)d_in[0];   // (16,1024,3)
    const float* C   = (const float*)d_in[1];   // (1024,3)
    const float* dom = (const float*)d_in[2];   // (16384,3)
    float* out = (float*)d_out;                 // (16,)

    char* ws = (char*)d_ws;
    float4* PDbin = (float4*)(ws + 0);          // 125*192*16    =  384000
    float4* C1col = (float4*)(ws + 384000);     // 16*25*96*16   =  614400 ->  998400
    float4* Ccol  = (float4*)(ws + 998400);     // 25*96*16      =   38400 -> 1036800
    float*  TC    = (float*)(ws + 1036800);     // 125*192*4     =   96000 -> 1132800
    int*    cnts  = (int*)(ws + 1132800);       // 569 words     -> ~1.14MB total

    hipMemsetAsync(cnts, 0, W_TOTAL * 4, stream);   // counters+ticket+barriers
    k_bin<<<GRID1, 256, 0, stream>>>(C1, C, dom, PDbin, C1col, Ccol, TC, cnts);
    k_main<<<MAIN_BLOCKS, 256, 0, stream>>>(PDbin, C1col, TC, cnts, out);
}

// Round 7
// 151.413 us; speedup vs baseline: 2.9685x; 2.9685x over previous
//
#include <hip/hip_runtime.h>
#include <math.h>

// L = 2*pi * log2(e): exp(-2pi r^2) == exp2(-L r^2)
#define LCONST 9.064720283654388f

// dom binned into 5x5x5 cells (size 2.0) over [0,10)^3; C1/C binned by (x,y)
// COLUMN only (25 columns). A cell's scan = <=9 CONTIGUOUS column runs; the
// missing z-filter is free because out-of-cutoff pairs underflow exp2 to 0.
// Cutoff r=2: dropped terms ~1.2e-11 vs theta ~0.36 -> below f32 ulp: exact.
#define NC 5
#define NCELL 125
#define NCOL 25
#define DOMCAP 192   // dom/cell: mean 131, sigma 11.4 -> +5.3 sigma (r2-r6 passed)
#define COLCAP 96    // pts/(b,col): mean 41, sigma 6.4 -> +8.6 sigma
#define NB 16
#define GRID_BIN 132              // 132*256 = 33792 = exactly all points to bin
#define IBLK 94                   // blocks per batch: 94*4 waves = 376 >= 375 tasks
#define MAIN_BLOCKS (NB * IBLK)   // 1504

// cnts word layout
#define W_CNTD 0      // 125
#define W_CNTC1 125   // 16*25 = 400
#define W_CNTC 525    // 25
#define W_PROD 550    // 16 floats
#define W_DONE 566    // block ticket
#define W_TOTAL 567

__device__ __forceinline__ float fexp2(float x) {
#if defined(__has_builtin)
#if __has_builtin(__builtin_amdgcn_exp2f)
    return __builtin_amdgcn_exp2f(x);
#else
    return exp2f(x);
#endif
#else
    return exp2f(x);
#endif
}

__device__ __forceinline__ int clamp5(float v) {
    int c = (int)(v * 0.5f);
    return c < 0 ? 0 : (c > NC - 1 ? NC - 1 : c);
}

// Full exponent arg = -L||d-q||^2 <= 0 stays in ONE exp2 argument (factoring
// exp2(d.w) out overflows: inf*0=NaN -- round-1 bug).
#define PAIR_ARG(d, q) fmaf((d).x, (q).x, fmaf((d).y, (q).y, fmaf((d).z, (q).z, (d).w + (q).w)))

// Scan the <=9 neighbor columns. Body is 8-wide: 8 independent wave-uniform
// loads in flight (round-0 proven structure). Tail handled by CLAMPED loads
// (never touch poisoned slots >= n) + wave-uniform select (dup contributions
// masked to 0). No padding phase, no barrier needed to build it.
__device__ __forceinline__ float scan9(float4 d, int cx, int cy,
                                       const float4* __restrict__ cols,
                                       const int* __restrict__ cnt) {
    float a0 = 0.f, a1 = 0.f, a2 = 0.f, a3 = 0.f;
    int xlo = cx > 0 ? cx - 1 : 0, xhi = cx < NC - 1 ? cx + 1 : NC - 1;
    int ylo = cy > 0 ? cy - 1 : 0, yhi = cy < NC - 1 ? cy + 1 : NC - 1;
    #pragma unroll 1
    for (int x2 = xlo; x2 <= xhi; ++x2) {
        #pragma unroll 1
        for (int y2 = ylo; y2 <= yhi; ++y2) {
            int col = x2 * NC + y2;
            int n = __builtin_amdgcn_readfirstlane(min(cnt[col], COLCAP));
            if (n == 0) continue;                       // wave-uniform
            const float4* __restrict__ p = cols + col * COLCAP;
            int nfull = n & ~7;
            int i = 0;
            #pragma unroll 1
            for (; i < nfull; i += 8) {
                float4 q0 = p[i],     q1 = p[i + 1], q2 = p[i + 2], q3 = p[i + 3];
                float4 q4 = p[i + 4], q5 = p[i + 5], q6 = p[i + 6], q7 = p[i + 7];
                a0 += fexp2(PAIR_ARG(d, q0)); a1 += fexp2(PAIR_ARG(d, q1));
                a2 += fexp2(PAIR_ARG(d, q2)); a3 += fexp2(PAIR_ARG(d, q3));
                a0 += fexp2(PAIR_ARG(d, q4)); a1 += fexp2(PAIR_ARG(d, q5));
                a2 += fexp2(PAIR_ARG(d, q6)); a3 += fexp2(PAIR_ARG(d, q7));
            }
            if (i < n) {                                // tail: <=7 valid points
                int m = n - 1;
                float4 q0 = p[i];
                float4 q1 = p[min(i + 1, m)], q2 = p[min(i + 2, m)];
                float4 q3 = p[min(i + 3, m)], q4 = p[min(i + 4, m)];
                float4 q5 = p[min(i + 5, m)], q6 = p[min(i + 6, m)];
                float4 q7 = p[min(i + 7, m)];
                a0 += fexp2(PAIR_ARG(d, q0));
                a1 += (i + 1 < n) ? fexp2(PAIR_ARG(d, q1)) : 0.f;
                a2 += (i + 2 < n) ? fexp2(PAIR_ARG(d, q2)) : 0.f;
                a3 += (i + 3 < n) ? fexp2(PAIR_ARG(d, q3)) : 0.f;
                a0 += (i + 4 < n) ? fexp2(PAIR_ARG(d, q4)) : 0.f;
                a1 += (i + 5 < n) ? fexp2(PAIR_ARG(d, q5)) : 0.f;
                a2 += (i + 6 < n) ? fexp2(PAIR_ARG(d, q6)) : 0.f;
                a3 += (i + 7 < n) ? fexp2(PAIR_ARG(d, q7)) : 0.f;
            }
        }
    }
    return (a0 + a1) + (a2 + a3);
}

// Pure binning -- no barriers, no fences. Cross-kernel visibility comes from
// the dispatch boundary. Slot order nondeterministic; sums order-free.
__global__ void __launch_bounds__(256) k_bin(const float* __restrict__ C1,
                                             const float* __restrict__ C,
                                             const float* __restrict__ dom,
                                             float4* __restrict__ PDbin,
                                             float4* __restrict__ C1col,
                                             float4* __restrict__ Ccol,
                                             int* __restrict__ cnts) {
    int* cntD  = cnts + W_CNTD;
    int* cntC1 = cnts + W_CNTC1;
    int* cntC  = cnts + W_CNTC;
    int t = blockIdx.x * 256 + threadIdx.x;   // 0..33791 exactly
    if (t < 16384) {
        float x = dom[3 * t], y = dom[3 * t + 1], z = dom[3 * t + 2];
        int cell = (clamp5(x) * NC + clamp5(y)) * NC + clamp5(z);
        int s = atomicAdd(cntD + cell, 1);
        if (s < DOMCAP)   // clamp: overflowed bins can't OOB
            PDbin[cell * DOMCAP + s] =
                make_float4(2.0f * LCONST * x, 2.0f * LCONST * y, 2.0f * LCONST * z,
                            -LCONST * (x * x + y * y + z * z));
    } else if (t < 32768) {
        int j = t - 16384;
        float x = C1[3 * j], y = C1[3 * j + 1], z = C1[3 * j + 2];
        int b = j >> 10;
        int col = clamp5(x) * NC + clamp5(y);
        int s = atomicAdd(cntC1 + b * NCOL + col, 1);
        if (s < COLCAP)
            C1col[(b * NCOL + col) * COLCAP + s] =
                make_float4(x, y, z, -LCONST * (x * x + y * y + z * z));
    } else {
        int j = t - 32768;
        float x = C[3 * j], y = C[3 * j + 1], z = C[3 * j + 2];
        int col = clamp5(x) * NC + clamp5(y);
        int s = atomicAdd(cntC + col, 1);
        if (s < COLCAP)
            Ccol[col * COLCAP + s] =
                make_float4(x, y, z, -LCONST * (x * x + y * y + z * z));
    }
}

// Block = (b, i): 4 waves = tasks 4i..4i+3 of 376 (task -> (cell,chunk); 375
// real). Each wave computes theta_b AND theta_C for its 64 dom points
// (theta_C recomputed per batch: +12us issue, but deletes the TC kernel, its
// barriers/fences, and a dispatch gap). ONE atomic per block; NO fences:
// prod-atomic ordered before ticket-atomic by s_waitcnt vmcnt(0) (atomic ack
// comes from the device coherence point); final block reads prod atomically.
__global__ void __launch_bounds__(256) k_main(const float4* __restrict__ PDbin,
                                              const float4* __restrict__ C1col,
                                              const float4* __restrict__ Ccol,
                                              int* __restrict__ cnts,
                                              float* __restrict__ out) {
    const int* cntD  = cnts + W_CNTD;
    const int* cntC1 = cnts + W_CNTC1;
    const int* cntC  = cnts + W_CNTC;
    float* prod = (float*)(cnts + W_PROD);
    unsigned* done = (unsigned*)(cnts + W_DONE);

    __shared__ float wsum[4];
    __shared__ int fin;

    int lane = threadIdx.x & 63, wid = threadIdx.x >> 6;
    int b = blockIdx.x / IBLK;
    int i = blockIdx.x - b * IBLK;
    int task = __builtin_amdgcn_readfirstlane(i * 4 + wid);   // 0..375
    int cell = task / 3, chunk = task - cell * 3;

    float v = 0.0f;
    if (cell < NCELL) {
        int len = __builtin_amdgcn_readfirstlane(min(cntD[cell], DOMCAP)) - chunk * 64;
        if (len > 0) {                        // wave-uniform
            int slot = cell * DOMCAP + chunk * 64 + lane;
            float4 d = make_float4(0.f, 0.f, 0.f, 0.f);   // sanitize poison lanes
            if (lane < len) d = PDbin[slot];
            int cx = cell / 25, cy = (cell / 5) % 5;
            float accb = scan9(d, cx, cy, C1col + (size_t)b * (NCOL * COLCAP),
                               cntC1 + b * NCOL);
            float accc = scan9(d, cx, cy, Ccol, cntC);
            v = (lane < len) ? accb * accc : 0.0f;        // select: NaN-safe
        }
    }
    for (int off = 32; off; off >>= 1) v += __shfl_down(v, off, 64);
    if (lane == 0) wsum[wid] = v;
    __syncthreads();
    if (threadIdx.x == 0) {
        atomicAdd(prod + b, wsum[0] + wsum[1] + wsum[2] + wsum[3]);
        asm volatile("s_waitcnt vmcnt(0)" ::: "memory");   // prod add performed
        unsigned old = atomicAdd(done, 1u);
        fin = (old == (unsigned)(MAIN_BLOCKS - 1)) ? 1 : 0;
    }
    __syncthreads();
    if (fin && threadIdx.x < 16) {
        const float scale = 4.76837158203125e-4f;  // A*V/1024
        float p = atomicAdd(prod + threadIdx.x, 0.0f);     // coherent read
        float dot = fminf(fmaxf(p * scale, 0.0f), 1.0f);
        out[threadIdx.x] = 1.0f - dot;
    }
}

extern "C" void kernel_launch(void* const* d_in, const int* in_sizes, int n_in,
                              void* d_out, int out_size, void* d_ws, size_t ws_size,
                              hipStream_t stream) {
    const float* C1  = (const float*)d_in[0];   // (16,1024,3)
    const float* C   = (const float*)d_in[1];   // (1024,3)
    const float* dom = (const float*)d_in[2];   // (16384,3)
    float* out = (float*)d_out;                 // (16,)

    char* ws = (char*)d_ws;
    float4* PDbin = (float4*)(ws + 0);          // 125*192*16   =  384000
    float4* C1col = (float4*)(ws + 384000);     // 16*25*96*16  =  614400 ->  998400
    float4* Ccol  = (float4*)(ws + 998400);     // 25*96*16     =   38400 -> 1036800
    int*    cnts  = (int*)(ws + 1036800);       // 567 words    -> ~1.04MB total

    hipMemsetAsync(cnts, 0, W_TOTAL * 4, stream);   // counters+prod+ticket
    k_bin<<<GRID_BIN, 256, 0, stream>>>(C1, C, dom, PDbin, C1col, Ccol, cnts);
    k_main<<<MAIN_BLOCKS, 256, 0, stream>>>(PDbin, C1col, Ccol, cnts, out);
}

// Round 8
// 129.028 us; speedup vs baseline: 3.4835x; 1.1735x over previous
//
#include <hip/hip_runtime.h>
#include <math.h>

// L = 2*pi * log2(e): exp(-2pi r^2) == exp2(-L r^2)
#define LCONST 9.064720283654388f

// dom binned into 5x5x5 cells (size 2.0) over [0,10)^3; C1/C binned by (x,y)
// COLUMN only (25 columns). A cell's neighborhood = <=9 columns; the missing
// z-filter is free because out-of-cutoff pairs underflow exp2 to 0.
// Cutoff r=2: dropped terms ~1.2e-11 vs theta ~0.36 -> below f32 ulp: exact.
#define NC 5
#define NCELL 125
#define NCOL 25
#define DOMCAP 192   // dom/cell: mean 131, sigma 11.4 -> +5.3 sigma (r2-r7 passed)
#define COLCAP 96    // pts/(b,col): mean 41, sigma 6.4 -> +8.6 sigma
#define NB 16
#define GRID_BIN 132              // 132*256 = 33792 = exactly all points to bin
#define MAIN_BLOCKS (NB * NCELL)  // 2000 blocks = one per (b,cell)
#define LCAP 544     // packed 9-col list cap: mean 277, sigma 19 -> +9 sigma; x8
#define DUMMYW -1.0e30f  // pad w: arg <= -1e30 -> exp2 = 0 exactly, no NaN path

// cnts word layout
#define W_CNTD 0      // 125
#define W_CNTC1 125   // 16*25 = 400
#define W_CNTC 525    // 25
#define W_PROD 550    // 16 floats
#define W_DONE 566    // block ticket
#define W_TOTAL 567

__device__ __forceinline__ float fexp2(float x) {
#if defined(__has_builtin)
#if __has_builtin(__builtin_amdgcn_exp2f)
    return __builtin_amdgcn_exp2f(x);
#else
    return exp2f(x);
#endif
#else
    return exp2f(x);
#endif
}

__device__ __forceinline__ int clamp5(float v) {
    int c = (int)(v * 0.5f);
    return c < 0 ? 0 : (c > NC - 1 ? NC - 1 : c);
}

// Full exponent arg = -L||d-q||^2 <= 0 stays in ONE exp2 argument (factoring
// exp2(d.w) out overflows: inf*0=NaN -- round-1 bug).
#define PAIR_ARG(d, q) fmaf((d).x, (q).x, fmaf((d).y, (q).y, fmaf((d).z, (q).z, (d).w + (q).w)))

// ONE long remainder-free unroll-8 LDS scan (r7 counters showed the 18-segment
// global-scan stalled on per-segment pipeline restarts: 38% VALUBusy). Uniform
// address ds_read_b128 = broadcast, conflict-free, ~120cyc latency covered by
// 8 independent reads in flight.
__device__ __forceinline__ float scan_lds(float4 d, const float4* __restrict__ sl,
                                          int n8) {
    float a0 = 0.f, a1 = 0.f, a2 = 0.f, a3 = 0.f;
    #pragma unroll 1
    for (int i = 0; i < n8; i += 8) {
        float4 q0 = sl[i],     q1 = sl[i + 1], q2 = sl[i + 2], q3 = sl[i + 3];
        float4 q4 = sl[i + 4], q5 = sl[i + 5], q6 = sl[i + 6], q7 = sl[i + 7];
        a0 += fexp2(PAIR_ARG(d, q0)); a1 += fexp2(PAIR_ARG(d, q1));
        a2 += fexp2(PAIR_ARG(d, q2)); a3 += fexp2(PAIR_ARG(d, q3));
        a0 += fexp2(PAIR_ARG(d, q4)); a1 += fexp2(PAIR_ARG(d, q5));
        a2 += fexp2(PAIR_ARG(d, q6)); a3 += fexp2(PAIR_ARG(d, q7));
    }
    return (a0 + a1) + (a2 + a3);
}

// Pure binning -- no barriers, no fences (r7 proven). Cross-kernel visibility
// from the dispatch boundary. Slot order nondeterministic; sums order-free.
__global__ void __launch_bounds__(256) k_bin(const float* __restrict__ C1,
                                             const float* __restrict__ C,
                                             const float* __restrict__ dom,
                                             float4* __restrict__ PDbin,
                                             float4* __restrict__ C1col,
                                             float4* __restrict__ Ccol,
                                             int* __restrict__ cnts) {
    int* cntD  = cnts + W_CNTD;
    int* cntC1 = cnts + W_CNTC1;
    int* cntC  = cnts + W_CNTC;
    int t = blockIdx.x * 256 + threadIdx.x;   // 0..33791 exactly
    if (t < 16384) {
        float x = dom[3 * t], y = dom[3 * t + 1], z = dom[3 * t + 2];
        int cell = (clamp5(x) * NC + clamp5(y)) * NC + clamp5(z);
        int s = atomicAdd(cntD + cell, 1);
        if (s < DOMCAP)   // clamp: overflowed bins can't OOB
            PDbin[cell * DOMCAP + s] =
                make_float4(2.0f * LCONST * x, 2.0f * LCONST * y, 2.0f * LCONST * z,
                            -LCONST * (x * x + y * y + z * z));
    } else if (t < 32768) {
        int j = t - 16384;
        float x = C1[3 * j], y = C1[3 * j + 1], z = C1[3 * j + 2];
        int b = j >> 10;
        int col = clamp5(x) * NC + clamp5(y);
        int s = atomicAdd(cntC1 + b * NCOL + col, 1);
        if (s < COLCAP)
            C1col[(b * NCOL + col) * COLCAP + s] =
                make_float4(x, y, z, -LCONST * (x * x + y * y + z * z));
    } else {
        int j = t - 32768;
        float x = C[3 * j], y = C[3 * j + 1], z = C[3 * j + 2];
        int col = clamp5(x) * NC + clamp5(y);
        int s = atomicAdd(cntC + col, 1);
        if (s < COLCAP)
            Ccol[col * COLCAP + s] =
                make_float4(x, y, z, -LCONST * (x * x + y * y + z * z));
    }
}

// Block = (b, cell): 192 threads = 3 chunk-waves of 64 dom points. Stage the
// 9-col neighborhoods of C1[b] and C into packed LDS lists once (parallel,
// coalesced, one barrier -- NOT r3's serial per-task staging), pad to x8 with
// dummies, then each wave runs two long remainder-free broadcast scans.
// Tail: one atomic per block + vmcnt-ordered ticket (r7 proven, fence-free).
__global__ void __launch_bounds__(192) k_main(const float4* __restrict__ PDbin,
                                              const float4* __restrict__ C1col,
                                              const float4* __restrict__ Ccol,
                                              int* __restrict__ cnts,
                                              float* __restrict__ out) {
    const int* cntD  = cnts + W_CNTD;
    const int* cntC1 = cnts + W_CNTC1;
    const int* cntC  = cnts + W_CNTC;
    float* prod = (float*)(cnts + W_PROD);
    unsigned* done = (unsigned*)(cnts + W_DONE);

    __shared__ float4 slB[LCAP];      // packed C1[b] neighborhood
    __shared__ float4 slC[LCAP];      // packed C neighborhood
    __shared__ int soffB[10], soffC[10];
    __shared__ float wsum[3];
    __shared__ int fin;

    int tid = threadIdx.x;
    int b = blockIdx.x / NCELL, cell = blockIdx.x - b * NCELL;
    int cx = cell / 25, cy = (cell / 5) % 5;
    int xlo = cx > 0 ? cx - 1 : 0, xhi = cx < NC - 1 ? cx + 1 : NC - 1;
    int ylo = cy > 0 ? cy - 1 : 0, yhi = cy < NC - 1 ? cy + 1 : NC - 1;
    int ny = yhi - ylo + 1;
    int ncols = (xhi - xlo + 1) * ny;          // 4..9, block-uniform
    const int* cb1 = cntC1 + b * NCOL;

    // exclusive prefix of the <=9 column counts (tiny, once per block)
    if (tid == 0) {
        int off = 0;
        for (int j = 0; j < ncols; ++j) {
            soffB[j] = off;
            int col = (xlo + j / ny) * NC + (ylo + j % ny);
            off += min(cb1[col], COLCAP);
        }
        soffB[9] = off;
    } else if (tid == 64) {
        int off = 0;
        for (int j = 0; j < ncols; ++j) {
            soffC[j] = off;
            int col = (xlo + j / ny) * NC + (ylo + j % ny);
            off += min(cntC[col], COLCAP);
        }
        soffC[9] = off;
    }
    __syncthreads();

    int nB = min(soffB[9], LCAP);              // block-uniform totals
    int nC = min(soffC[9], LCAP);

    // stage: 2 columns per round x 5 rounds covers <=9 columns; coalesced
    // 16B/thread global loads -> LDS. Guards: never read slots >= cnt (poison),
    // never write >= LCAP (overflow clamp).
    int half = tid / 96;                       // 0|1
    int e = tid - half * 96;                   // 0..95
    #pragma unroll
    for (int r = 0; r < 5; ++r) {
        int j = 2 * r + half;
        if (j < ncols) {
            int col = (xlo + j / ny) * NC + (ylo + j % ny);
            int c1 = min(cb1[col], COLCAP);
            int d1 = soffB[j] + e;
            if (e < c1 && d1 < LCAP)
                slB[d1] = C1col[(size_t)(b * NCOL + col) * COLCAP + e];
            int cc = min(cntC[col], COLCAP);
            int dc = soffC[j] + e;
            if (e < cc && dc < LCAP)
                slC[dc] = Ccol[col * COLCAP + e];
        }
    }
    // pad both lists to a multiple of 8 with exp2->0 dummies (disjoint slots)
    if (tid < 8) {
        int nB8 = (nB + 7) & ~7;
        if (nB + tid < nB8) slB[nB + tid] = make_float4(0.f, 0.f, 0.f, DUMMYW);
        int nC8 = (nC + 7) & ~7;
        if (nC + tid < nC8) slC[nC + tid] = make_float4(0.f, 0.f, 0.f, DUMMYW);
    }
    __syncthreads();

    int lane = tid & 63;
    int len = __builtin_amdgcn_readfirstlane(min(cntD[cell], DOMCAP));
    float v = 0.0f;
    if ((tid & ~63) < len) {                   // wave-uniform live check
        float4 d = make_float4(0.f, 0.f, 0.f, 0.f);   // sanitize poison lanes
        if (tid < len) d = PDbin[cell * DOMCAP + tid];
        int nB8 = __builtin_amdgcn_readfirstlane((nB + 7) & ~7);
        int nC8 = __builtin_amdgcn_readfirstlane((nC + 7) & ~7);
        float accb = scan_lds(d, slB, nB8);    // theta_b
        float accc = scan_lds(d, slC, nC8);    // theta_C (redundant per b; no
                                               // extra dispatch/barrier needed)
        v = (tid < len) ? accb * accc : 0.0f;  // select, not multiply: NaN-safe
    }
    for (int off = 32; off; off >>= 1) v += __shfl_down(v, off, 64);
    if (lane == 0) wsum[tid >> 6] = v;
    __syncthreads();
    if (tid == 0) {
        atomicAdd(prod + b, wsum[0] + wsum[1] + wsum[2]);
        asm volatile("s_waitcnt vmcnt(0)" ::: "memory");   // prod add performed
        unsigned old = atomicAdd(done, 1u);
        fin = (old == (unsigned)(MAIN_BLOCKS - 1)) ? 1 : 0;
    }
    __syncthreads();
    if (fin && tid < 16) {
        const float scale = 4.76837158203125e-4f;  // A*V/1024
        float p = atomicAdd(prod + tid, 0.0f);     // coherent read
        float dot = fminf(fmaxf(p * scale, 0.0f), 1.0f);
        out[tid] = 1.0f - dot;
    }
}

extern "C" void kernel_launch(void* const* d_in, const int* in_sizes, int n_in,
                              void* d_out, int out_size, void* d_ws, size_t ws_size,
                              hipStream_t stream) {
    const float* C1  = (const float*)d_in[0];   // (16,1024,3)
    const float* C   = (const float*)d_in[1];   // (1024,3)
    const float* dom = (const float*)d_in[2];   // (16384,3)
    float* out = (float*)d_out;                 // (16,)

    char* ws = (char*)d_ws;
    float4* PDbin = (float4*)(ws + 0);          // 125*192*16   =  384000
    float4* C1col = (float4*)(ws + 384000);     // 16*25*96*16  =  614400 ->  998400
    float4* Ccol  = (float4*)(ws + 998400);     // 25*96*16     =   38400 -> 1036800
    int*    cnts  = (int*)(ws + 1036800);       // 567 words    -> ~1.04MB total

    hipMemsetAsync(cnts, 0, W_TOTAL * 4, stream);   // counters+prod+ticket
    k_bin<<<GRID_BIN, 256, 0, stream>>>(C1, C, dom, PDbin, C1col, Ccol, cnts);
    k_main<<<MAIN_BLOCKS, 192, 0, stream>>>(PDbin, C1col, Ccol, cnts, out);
}